// Round 10
// baseline (663.755 us; speedup 1.0000x reference)
//
#include <hip/hip_runtime.h>
#include <hip/hip_bf16.h>
#include <stdint.h>

#define SS 144
#define DD 1024
#define NB 128
#define SP 160          // padded S for the PV K-dimension
#define SCALE 0.03125f  // 1024^-0.5

typedef __attribute__((ext_vector_type(8))) short short8;   // 8 bf16 = 4 VGPRs
typedef __attribute__((ext_vector_type(4))) float floatx4;
typedef unsigned short u16;

#define MFMA(a, b, c) __builtin_amdgcn_mfma_f32_16x16x32_bf16((a), (b), (c), 0, 0, 0)

__device__ __forceinline__ u16 f2bf(float f) {
    union { float f; unsigned int i; } v; v.f = f;
    unsigned int r = v.i + 0x7fff + ((v.i >> 16) & 1);   // RNE
    return (u16)(r >> 16);
}
__device__ __forceinline__ short8 pack8(float4 a, float4 b) {
    short8 r;
    r[0] = (short)f2bf(a.x); r[1] = (short)f2bf(a.y);
    r[2] = (short)f2bf(a.z); r[3] = (short)f2bf(a.w);
    r[4] = (short)f2bf(b.x); r[5] = (short)f2bf(b.y);
    r[6] = (short)f2bf(b.z); r[7] = (short)f2bf(b.w);
    return r;
}

// async global->LDS, 16B per lane. LDS dest must be wave-uniform base + lane*16.
__device__ __forceinline__ void gload16(u16* lds, const u16* g) {
    __builtin_amdgcn_global_load_lds(
        (__attribute__((address_space(1))) void*)g,
        (__attribute__((address_space(3))) void*)lds, 16, 0, 0);
}

// ---- 0. fp32 -> bf16 convert, all three inputs in one dispatch ----------
__global__ __launch_bounds__(256) void convert3_k(
    const float* __restrict__ Xq, const float* __restrict__ Xk,
    const float* __restrict__ Xv,
    u16* __restrict__ Oq, u16* __restrict__ Ok, u16* __restrict__ Ov, int nchunk) {
    int z = blockIdx.y;
    const float* X = z == 0 ? Xq : (z == 1 ? Xk : Xv);
    u16* O = z == 0 ? Oq : (z == 1 ? Ok : Ov);
    for (int c = blockIdx.x * 256 + threadIdx.x; c < nchunk; c += gridDim.x * 256) {
        size_t i = (size_t)c * 8;
        float4 a = *(const float4*)(X + i);
        float4 b = *(const float4*)(X + i + 4);
        *(short8*)(O + i) = pack8(a, b);
    }
}

// ---- 1. transpose+convert Wq/Wk/Wv fp32 (K,N) -> WT bf16 (N,K) ----------
__global__ void transpose_w_k(const float* __restrict__ Wq, const float* __restrict__ Wk,
                              const float* __restrict__ Wv, u16* __restrict__ WT) {
    __shared__ u16 t[32][33];
    int z = blockIdx.z;
    const float* W = z == 0 ? Wq : (z == 1 ? Wk : Wv);
    u16* O = WT + (size_t)z * DD * DD;
    int bn = blockIdx.x * 32, bk = blockIdx.y * 32;
    int tx = threadIdx.x & 31, ty = threadIdx.x >> 5;
    for (int r = ty; r < 32; r += 8) t[r][tx] = f2bf(W[(size_t)(bk + r) * DD + bn + tx]);
    __syncthreads();
    for (int r = ty; r < 32; r += 8) O[(size_t)(bn + r) * DD + bk + tx] = t[tx][r];
}

// ---- 2. relative-position bias (S,S) fp32; dw=dh=0 exactly --------------
__global__ void bias_k(const float* __restrict__ Wl, const float* __restrict__ bl,
                       const float* __restrict__ wg, float* __restrict__ biasb) {
    int ij = blockIdx.x;
    int i = ij / SS, j = ij - i * SS;
    int lane = threadIdx.x;
    int ri = i / 12, ci = i - ri * 12, rj = j / 12, cj = j - rj * 12;
    float dx = logf(fmaxf(fabsf((float)(ri - rj)) * 0.5f, 1e-10f));
    float dy = logf(fmaxf(fabsf((float)(ci - cj)) * 0.5f, 1e-10f));
    float s = 0.f;
    for (int d = lane; d < DD; d += 64) {
        float r = dx * Wl[d] + dy * Wl[DD + d] + bl[d];
        r = fmaxf(r, 0.f);
        s += r * wg[(size_t)i * DD + d];
    }
    #pragma unroll
    for (int m = 32; m > 0; m >>= 1) s += __shfl_xor(s, m);
    if (lane == 0) biasb[ij] = fmaxf(s, 0.f);
}

// ---- 3. projection GEMM: relu(Xbf @ W + b) ------------------------------
// r5 measured-best config: single dispatch, grid (8,144,3), bn fastest
// (B-panels L2-hot). r3 K-loop verbatim.
// z=0 -> q bf16 (M,N), z=1 -> k bf16 (M,N), z=2 -> vT bf16 (B, D, SP).
__global__ __launch_bounds__(256) void proj_k(
    const u16* __restrict__ Xq, const u16* __restrict__ Xk, const u16* __restrict__ Xv,
    const u16* __restrict__ WT,
    const float* __restrict__ bq, const float* __restrict__ bk, const float* __restrict__ bv,
    u16* __restrict__ Oq, u16* __restrict__ Ok, u16* __restrict__ OvT) {
    __shared__ __align__(16) u16 As[128 * 32];
    __shared__ __align__(16) u16 Bs[128 * 32];
    int z = blockIdx.z;
    const u16* Xb = z == 0 ? Xq : (z == 1 ? Xk : Xv);
    const u16* Wt = WT + (size_t)z * DD * DD;
    const float* bias = z == 0 ? bq : (z == 1 ? bk : bv);
    int bn = blockIdx.x, bm = blockIdx.y;
    int tid = threadIdx.x, lane = tid & 63, wv = tid >> 6;
    int wm = wv >> 1, wn = wv & 1;
    int lr = lane & 15, lq = lane >> 4;

    floatx4 zero4 = {0.f, 0.f, 0.f, 0.f};
    floatx4 acc[4][4];
    #pragma unroll
    for (int r = 0; r < 4; r++)
        #pragma unroll
        for (int c = 0; c < 4; c++) acc[r][c] = zero4;

    const u16* Abase = Xb + (size_t)bm * 128 * DD;
    const u16* Bbase = Wt + (size_t)bn * 128 * DD;

    int c0 = tid, c1 = tid + 256;
    const u16* ga0 = Abase + (size_t)(c0 >> 2) * DD + ((c0 & 3) << 3);
    const u16* ga1 = Abase + (size_t)(c1 >> 2) * DD + ((c1 & 3) << 3);
    const u16* gb0 = Bbase + (size_t)(c0 >> 2) * DD + ((c0 & 3) << 3);
    const u16* gb1 = Bbase + (size_t)(c1 >> 2) * DD + ((c1 & 3) << 3);
    u16* la0 = &As[c0 * 8];
    u16* la1 = &As[c1 * 8];
    u16* lb0 = &Bs[c0 * 8];
    u16* lb1 = &Bs[c1 * 8];

    for (int k0 = 0; k0 < DD; k0 += 32) {
        __syncthreads();            // previous iteration's ds_reads complete
        gload16(la0, ga0 + k0);
        gload16(la1, ga1 + k0);
        gload16(lb0, gb0 + k0);
        gload16(lb1, gb1 + k0);
        __syncthreads();            // drains vmcnt -> tiles ready
        short8 a[4], b[4];
        #pragma unroll
        for (int r = 0; r < 4; r++)
            a[r] = *(const short8*)&As[(wm * 64 + r * 16 + lr) * 32 + lq * 8];
        #pragma unroll
        for (int c = 0; c < 4; c++)
            b[c] = *(const short8*)&Bs[(wn * 64 + c * 16 + lr) * 32 + lq * 8];
        #pragma unroll
        for (int r = 0; r < 4; r++)
            #pragma unroll
            for (int c = 0; c < 4; c++)
                acc[r][c] = MFMA(a[r], b[c], acc[r][c]);
    }

    int mrow0 = bm * 128 + wm * 64;
    int ncol0 = bn * 128 + wn * 64;
    if (z < 2) {
        u16* O = z == 0 ? Oq : Ok;
        #pragma unroll
        for (int r = 0; r < 4; r++)
            #pragma unroll
            for (int c = 0; c < 4; c++) {
                int col = ncol0 + c * 16 + lr;
                float bb = bias[col];
                #pragma unroll
                for (int i = 0; i < 4; i++) {
                    int row = mrow0 + r * 16 + lq * 4 + i;
                    O[(size_t)row * DD + col] = f2bf(fmaxf(acc[r][c][i] + bb, 0.f));
                }
            }
    } else {
        #pragma unroll
        for (int r = 0; r < 4; r++)
            #pragma unroll
            for (int c = 0; c < 4; c++) {
                int col = ncol0 + c * 16 + lr;
                float bb = bias[col];
                #pragma unroll
                for (int i = 0; i < 4; i++) {
                    int row = mrow0 + r * 16 + lq * 4 + i;
                    int bidx = row / SS;
                    int srow = row - bidx * SS;
                    OvT[((size_t)bidx * DD + col) * SP + srow] =
                        f2bf(fmaxf(acc[r][c][i] + bb, 0.f));
                }
            }
    }
}

// ---- 4. fused attention: ONE block per batch element --------------------
// 576 threads = 9 waves; wave w owns score rows [w*16, w*16+16).
// k[b] staged in LDS once (9x traffic cut); softmax in registers;
// probs -> Pst LDS (bf16, zero-padded to SP); PV: wave w owns 128 out
// cols, vT cols read ONCE into registers (9x traffic cut).
// LDS union: kst[144][72] (phase 1) / Pst[144][168] (phases 2-3), 48.4 KB.
__global__ __launch_bounds__(576) void attn_fused_k(
    const u16* __restrict__ q, const u16* __restrict__ k,
    const u16* __restrict__ vT, const float* __restrict__ biasb,
    float* __restrict__ out) {
    __shared__ __align__(16) u16 smem[24192];   // 48384 B
    u16* kst = smem;                             // [144][72]
    u16* Pst = smem;                             // [144][168]
    int b = blockIdx.x;
    int tid = threadIdx.x, lane = tid & 63, wv = tid >> 6;   // wv 0..8
    int lr = lane & 15, lq = lane >> 4;
    const u16* qs = q + (size_t)b * SS * DD;
    const u16* ks = k + (size_t)b * SS * DD;

    // ---- phase 1: QK^T with K in LDS (64-wide d0 chunks) ----
    floatx4 acc[9];
    #pragma unroll
    for (int c = 0; c < 9; c++) acc[c] = (floatx4){0.f, 0.f, 0.f, 0.f};
    // staging: 1152 chunks of 16B; thread t -> chunks t, t+576
    int c0 = tid, c1 = tid + 576;
    int r0 = c0 >> 3, o0 = (c0 & 7) << 3;
    int r1 = c1 >> 3, o1 = (c1 & 7) << 3;
    int qrow = wv * 16 + lr;
    for (int d0 = 0; d0 < DD; d0 += 64) {
        short8 v0 = *(const short8*)&ks[(size_t)r0 * DD + d0 + o0];
        short8 v1 = *(const short8*)&ks[(size_t)r1 * DD + d0 + o1];
        short8 a0 = *(const short8*)&qs[(size_t)qrow * DD + d0 + lq * 8];
        short8 a1 = *(const short8*)&qs[(size_t)qrow * DD + d0 + 32 + lq * 8];
        __syncthreads();             // prior chunk's kst reads complete
        *(short8*)&kst[r0 * 72 + o0] = v0;
        *(short8*)&kst[r1 * 72 + o1] = v1;
        __syncthreads();             // staging visible
        #pragma unroll
        for (int ct = 0; ct < 9; ct++) {
            short8 b0 = *(const short8*)&kst[(ct * 16 + lr) * 72 + lq * 8];
            acc[ct] = MFMA(a0, b0, acc[ct]);
        }
        #pragma unroll
        for (int ct = 0; ct < 9; ct++) {
            short8 b1 = *(const short8*)&kst[(ct * 16 + lr) * 72 + 32 + lq * 8];
            acc[ct] = MFMA(a1, b1, acc[ct]);
        }
    }
    __syncthreads();   // all kst reads done before Pst overwrite

    // ---- phase 2: softmax in registers; rows row0..row0+3 ----
    int row0 = wv * 16 + lq * 4;
    float sv[9][4], mx[4], sm[4];
    #pragma unroll
    for (int i = 0; i < 4; i++) mx[i] = -1e30f;
    #pragma unroll
    for (int ct = 0; ct < 9; ct++)
        #pragma unroll
        for (int i = 0; i < 4; i++) {
            float s = acc[ct][i] * SCALE + biasb[(row0 + i) * SS + ct * 16 + lr];
            sv[ct][i] = s;
            mx[i] = fmaxf(mx[i], s);
        }
    #pragma unroll
    for (int i = 0; i < 4; i++) {
        #pragma unroll
        for (int m = 1; m < 16; m <<= 1) mx[i] = fmaxf(mx[i], __shfl_xor(mx[i], m));
        sm[i] = 0.f;
    }
    #pragma unroll
    for (int ct = 0; ct < 9; ct++)
        #pragma unroll
        for (int i = 0; i < 4; i++) {
            float e = expf(sv[ct][i] - mx[i]);
            sv[ct][i] = e;
            sm[i] += e;
        }
    #pragma unroll
    for (int i = 0; i < 4; i++) {
        #pragma unroll
        for (int m = 1; m < 16; m <<= 1) sm[i] += __shfl_xor(sm[i], m);
        sm[i] = 1.f / sm[i];
    }
    #pragma unroll
    for (int ct = 0; ct < 9; ct++)
        #pragma unroll
        for (int i = 0; i < 4; i++)
            Pst[(row0 + i) * 168 + ct * 16 + lr] = f2bf(sv[ct][i] * sm[i]);
    #pragma unroll
    for (int i = 0; i < 4; i++)          // zero-pad cols 144..159
        Pst[(row0 + i) * 168 + 144 + lr] = 0;
    __syncthreads();

    // ---- phase 3: PV; wave wv<8 owns out cols [wv*128, wv*128+128) ----
    if (wv < 8) {
        const u16* vt = vT + (size_t)b * DD * SP;
        float* ob = out + (size_t)b * SS * DD;
        int colb = wv * 128;
        for (int ct2 = 0; ct2 < 8; ct2++) {
            int col = colb + ct2 * 16 + lr;
            short8 vb[5];
            #pragma unroll
            for (int kk = 0; kk < 5; kk++)
                vb[kk] = *(const short8*)&vt[(size_t)col * SP + kk * 32 + lq * 8];
            for (int rt = 0; rt < 9; rt++) {
                floatx4 f = {0.f, 0.f, 0.f, 0.f};
                #pragma unroll
                for (int kk = 0; kk < 5; kk++) {
                    short8 a = *(const short8*)&Pst[(rt * 16 + lr) * 168 + kk * 32 + lq * 8];
                    f = MFMA(a, vb[kk], f);
                }
                #pragma unroll
                for (int i = 0; i < 4; i++)
                    ob[(size_t)(rt * 16 + lq * 4 + i) * DD + col] = f[i];
            }
        }
    }
}

extern "C" void kernel_launch(void* const* d_in, const int* in_sizes, int n_in,
                              void* d_out, int out_size, void* d_ws, size_t ws_size,
                              hipStream_t stream) {
    const float* query = (const float*)d_in[0];
    const float* key_  = (const float*)d_in[1];
    const float* value = (const float*)d_in[2];
    const float* Wq = (const float*)d_in[3];
    const float* bq = (const float*)d_in[4];
    const float* Wk = (const float*)d_in[5];
    const float* bk = (const float*)d_in[6];
    const float* Wv = (const float*)d_in[7];
    const float* bv = (const float*)d_in[8];
    const float* Wl = (const float*)d_in[9];
    const float* bl = (const float*)d_in[10];
    const float* wg = (const float*)d_in[11];

    // ws layout (bf16 elements unless noted)
    u16* WT    = (u16*)d_ws;                              // 3*1024*1024
    u16* Xv    = WT + (size_t)3 * DD * DD;                // 18432*1024 (value bf16)
    u16* q     = Xv + (size_t)NB * SS * DD;               // 18432*1024
    u16* k     = q  + (size_t)NB * SS * DD;
    u16* vT    = k  + (size_t)NB * SS * DD;               // 128*1024*160
    float* biasb = (float*)(vT + (size_t)NB * DD * SP);   // 144*144 f32

    // d_out (75.5 MB fp32) is dead until attn_fused_k -> bf16 scratch for
    // converted query/key (exactly 2 * 128*144*1024 * 2B).
    u16* Xq = (u16*)d_out;
    u16* Xk = Xq + (size_t)NB * SS * DD;

    transpose_w_k<<<dim3(32, 32, 3), 256, 0, stream>>>(Wq, Wk, Wv, WT);
    bias_k<<<dim3(SS * SS), 64, 0, stream>>>(Wl, bl, wg, biasb);

    int nchunk = NB * SS * DD / 8;
    convert3_k<<<dim3(1024, 3), 256, 0, stream>>>(query, key_, value, Xq, Xk, Xv, nchunk);
    proj_k<<<dim3(8, 144, 3), 256, 0, stream>>>(Xq, Xk, Xv, WT, bq, bk, bv, q, k, vT);

    attn_fused_k<<<dim3(NB), 576, 0, stream>>>(q, k, vT, biasb, (float*)d_out);
}

// Round 11
// 619.261 us; speedup vs baseline: 1.0718x; 1.0718x over previous
//
#include <hip/hip_runtime.h>
#include <hip/hip_bf16.h>
#include <stdint.h>

#define SS 144
#define DD 1024
#define NB 128
#define SP 160          // padded S for the PV K-dimension
#define SCALE 0.03125f  // 1024^-0.5

typedef __attribute__((ext_vector_type(8))) short short8;   // 8 bf16 = 4 VGPRs
typedef __attribute__((ext_vector_type(4))) float floatx4;
typedef unsigned short u16;

#define MFMA(a, b, c) __builtin_amdgcn_mfma_f32_16x16x32_bf16((a), (b), (c), 0, 0, 0)

__device__ __forceinline__ u16 f2bf(float f) {
    union { float f; unsigned int i; } v; v.f = f;
    unsigned int r = v.i + 0x7fff + ((v.i >> 16) & 1);   // RNE
    return (u16)(r >> 16);
}
__device__ __forceinline__ short8 pack8(float4 a, float4 b) {
    short8 r;
    r[0] = (short)f2bf(a.x); r[1] = (short)f2bf(a.y);
    r[2] = (short)f2bf(a.z); r[3] = (short)f2bf(a.w);
    r[4] = (short)f2bf(b.x); r[5] = (short)f2bf(b.y);
    r[6] = (short)f2bf(b.z); r[7] = (short)f2bf(b.w);
    return r;
}

// async global->LDS, 16B per lane. LDS dest must be wave-uniform base + lane*16.
__device__ __forceinline__ void gload16(u16* lds, const u16* g) {
    __builtin_amdgcn_global_load_lds(
        (__attribute__((address_space(1))) void*)g,
        (__attribute__((address_space(3))) void*)lds, 16, 0, 0);
}

// ---- 0. fp32 -> bf16 convert, all three inputs in one dispatch ----------
__global__ __launch_bounds__(256) void convert3_k(
    const float* __restrict__ Xq, const float* __restrict__ Xk,
    const float* __restrict__ Xv,
    u16* __restrict__ Oq, u16* __restrict__ Ok, u16* __restrict__ Ov, int nchunk) {
    int z = blockIdx.y;
    const float* X = z == 0 ? Xq : (z == 1 ? Xk : Xv);
    u16* O = z == 0 ? Oq : (z == 1 ? Ok : Ov);
    for (int c = blockIdx.x * 256 + threadIdx.x; c < nchunk; c += gridDim.x * 256) {
        size_t i = (size_t)c * 8;
        float4 a = *(const float4*)(X + i);
        float4 b = *(const float4*)(X + i + 4);
        *(short8*)(O + i) = pack8(a, b);
    }
}

// ---- 1. transpose+convert Wq/Wk/Wv fp32 (K,N) -> WT bf16 (N,K) ----------
__global__ void transpose_w_k(const float* __restrict__ Wq, const float* __restrict__ Wk,
                              const float* __restrict__ Wv, u16* __restrict__ WT) {
    __shared__ u16 t[32][33];
    int z = blockIdx.z;
    const float* W = z == 0 ? Wq : (z == 1 ? Wk : Wv);
    u16* O = WT + (size_t)z * DD * DD;
    int bn = blockIdx.x * 32, bk = blockIdx.y * 32;
    int tx = threadIdx.x & 31, ty = threadIdx.x >> 5;
    for (int r = ty; r < 32; r += 8) t[r][tx] = f2bf(W[(size_t)(bk + r) * DD + bn + tx]);
    __syncthreads();
    for (int r = ty; r < 32; r += 8) O[(size_t)(bn + r) * DD + bk + tx] = t[tx][r];
}

// ---- 2. relative-position bias (S,S) fp32; dw=dh=0 exactly --------------
__global__ void bias_k(const float* __restrict__ Wl, const float* __restrict__ bl,
                       const float* __restrict__ wg, float* __restrict__ biasb) {
    int ij = blockIdx.x;
    int i = ij / SS, j = ij - i * SS;
    int lane = threadIdx.x;
    int ri = i / 12, ci = i - ri * 12, rj = j / 12, cj = j - rj * 12;
    float dx = logf(fmaxf(fabsf((float)(ri - rj)) * 0.5f, 1e-10f));
    float dy = logf(fmaxf(fabsf((float)(ci - cj)) * 0.5f, 1e-10f));
    float s = 0.f;
    for (int d = lane; d < DD; d += 64) {
        float r = dx * Wl[d] + dy * Wl[DD + d] + bl[d];
        r = fmaxf(r, 0.f);
        s += r * wg[(size_t)i * DD + d];
    }
    #pragma unroll
    for (int m = 32; m > 0; m >>= 1) s += __shfl_xor(s, m);
    if (lane == 0) biasb[ij] = fmaxf(s, 0.f);
}

// ---- 3. projection GEMM: relu(Xbf @ W + b) ------------------------------
// r5 structure + XOR bank-swizzle (rule #21: LDS dest stays lane-linear;
// the per-lane GLOBAL source is inverse-permuted; ds_read applies the same
// permutation). chunk c=(row=c>>2,kg=c&3): slot kg holds global piece
// kg ^ ((row>>1)&3); read uses kg_phys = lq ^ ((lr>>1)&3).
// 16 lanes -> 8 distinct 16B slots -> 2-way (free) instead of 8-way.
// Global footprint per 4-lane group unchanged (same 64B line, permuted).
// z=0 -> q bf16 (M,N), z=1 -> k bf16 (M,N), z=2 -> vT bf16 (B, D, SP).
__global__ __launch_bounds__(256) void proj_k(
    const u16* __restrict__ Xq, const u16* __restrict__ Xk, const u16* __restrict__ Xv,
    const u16* __restrict__ WT,
    const float* __restrict__ bq, const float* __restrict__ bk, const float* __restrict__ bv,
    u16* __restrict__ Oq, u16* __restrict__ Ok, u16* __restrict__ OvT) {
    __shared__ __align__(16) u16 As[128 * 32];
    __shared__ __align__(16) u16 Bs[128 * 32];
    int z = blockIdx.z;
    const u16* Xb = z == 0 ? Xq : (z == 1 ? Xk : Xv);
    const u16* Wt = WT + (size_t)z * DD * DD;
    const float* bias = z == 0 ? bq : (z == 1 ? bk : bv);
    int bn = blockIdx.x, bm = blockIdx.y;
    int tid = threadIdx.x, lane = tid & 63, wv = tid >> 6;
    int wm = wv >> 1, wn = wv & 1;
    int lr = lane & 15, lq = lane >> 4;

    floatx4 zero4 = {0.f, 0.f, 0.f, 0.f};
    floatx4 acc[4][4];
    #pragma unroll
    for (int r = 0; r < 4; r++)
        #pragma unroll
        for (int c = 0; c < 4; c++) acc[r][c] = zero4;

    const u16* Abase = Xb + (size_t)bm * 128 * DD;
    const u16* Bbase = Wt + (size_t)bn * 128 * DD;

    // swizzled staging: chunk c -> row c>>2; global k-offset uses
    // kg_log = (c&3) ^ ((row>>1)&3). LDS byte offset stays c*16.
    int c0 = tid, c1 = tid + 256;
    int r0c = c0 >> 2, r1c = c1 >> 2;
    int ko0 = (((c0 & 3) ^ ((r0c >> 1) & 3)) << 3);
    int ko1 = (((c1 & 3) ^ ((r1c >> 1) & 3)) << 3);
    const u16* ga0 = Abase + (size_t)r0c * DD + ko0;
    const u16* ga1 = Abase + (size_t)r1c * DD + ko1;
    const u16* gb0 = Bbase + (size_t)r0c * DD + ko0;
    const u16* gb1 = Bbase + (size_t)r1c * DD + ko1;
    u16* la0 = &As[c0 * 8];
    u16* la1 = &As[c1 * 8];
    u16* lb0 = &Bs[c0 * 8];
    u16* lb1 = &Bs[c1 * 8];

    // read-side swizzle: fragment rows are base+lr; (row>>1)&3 == (lr>>1)&3
    // because the base (wm*64 + r*16) is a multiple of 16.
    int kq = ((lq ^ ((lr >> 1) & 3)) << 3);

    for (int k0 = 0; k0 < DD; k0 += 32) {
        __syncthreads();            // previous iteration's ds_reads complete
        gload16(la0, ga0 + k0);
        gload16(la1, ga1 + k0);
        gload16(lb0, gb0 + k0);
        gload16(lb1, gb1 + k0);
        __syncthreads();            // drains vmcnt -> tiles ready
        short8 a[4], b[4];
        #pragma unroll
        for (int r = 0; r < 4; r++)
            a[r] = *(const short8*)&As[(wm * 64 + r * 16 + lr) * 32 + kq];
        #pragma unroll
        for (int c = 0; c < 4; c++)
            b[c] = *(const short8*)&Bs[(wn * 64 + c * 16 + lr) * 32 + kq];
        #pragma unroll
        for (int r = 0; r < 4; r++)
            #pragma unroll
            for (int c = 0; c < 4; c++)
                acc[r][c] = MFMA(a[r], b[c], acc[r][c]);
    }

    int mrow0 = bm * 128 + wm * 64;
    int ncol0 = bn * 128 + wn * 64;
    if (z < 2) {
        u16* O = z == 0 ? Oq : Ok;
        #pragma unroll
        for (int r = 0; r < 4; r++)
            #pragma unroll
            for (int c = 0; c < 4; c++) {
                int col = ncol0 + c * 16 + lr;
                float bb = bias[col];
                #pragma unroll
                for (int i = 0; i < 4; i++) {
                    int row = mrow0 + r * 16 + lq * 4 + i;
                    O[(size_t)row * DD + col] = f2bf(fmaxf(acc[r][c][i] + bb, 0.f));
                }
            }
    } else {
        #pragma unroll
        for (int r = 0; r < 4; r++)
            #pragma unroll
            for (int c = 0; c < 4; c++) {
                int col = ncol0 + c * 16 + lr;
                float bb = bias[col];
                #pragma unroll
                for (int i = 0; i < 4; i++) {
                    int row = mrow0 + r * 16 + lq * 4 + i;
                    int bidx = row / SS;
                    int srow = row - bidx * SS;
                    OvT[((size_t)bidx * DD + col) * SP + srow] =
                        f2bf(fmaxf(acc[r][c][i] + bb, 0.f));
                }
            }
    }
}

// ---- 4. scores + bias + softmax -> probs (bf16, zero-padded to SP) ------
__global__ __launch_bounds__(256) void attn_k(
    const u16* __restrict__ q, const u16* __restrict__ k,
    const float* __restrict__ biasb, u16* __restrict__ probs) {
    __shared__ float Sst[16][148];
    int it = blockIdx.x, b = blockIdx.y;
    int i0 = it * 16;
    int tid = threadIdx.x, lane = tid & 63, wv = tid >> 6;
    int lr = lane & 15, lq = lane >> 4;
    const u16* qs = q + ((size_t)b * SS + i0) * DD;
    const u16* ks = k + (size_t)b * SS * DD;

    floatx4 zero4 = {0.f, 0.f, 0.f, 0.f};
    floatx4 acc[3] = {zero4, zero4, zero4};
    int nt = (wv == 0) ? 3 : 2;  // wave w handles col-tiles {w, w+4, w+8<9}

    for (int d0 = 0; d0 < DD; d0 += 32) {
        short8 a = *(const short8*)&qs[(size_t)lr * DD + d0 + lq * 8];
        #pragma unroll
        for (int m = 0; m < 3; m++) {
            if (m < nt) {
                int t = wv + m * 4;
                short8 bb = *(const short8*)&ks[(size_t)(t * 16 + lr) * DD + d0 + lq * 8];
                acc[m] = MFMA(a, bb, acc[m]);
            }
        }
    }
    for (int m = 0; m < nt; m++) {
        int t = wv + m * 4;
        #pragma unroll
        for (int i = 0; i < 4; i++) {
            int row = lq * 4 + i, col = t * 16 + lr;
            Sst[row][col] = acc[m][i] * SCALE + biasb[(i0 + row) * SS + col];
        }
    }
    __syncthreads();

    int g = tid >> 4, j = tid & 15;  // 16-lane subgroup g owns row g
    float mx = -1e30f;
    for (int c = j; c < SS; c += 16) mx = fmaxf(mx, Sst[g][c]);
    #pragma unroll
    for (int m = 1; m < 16; m <<= 1) mx = fmaxf(mx, __shfl_xor(mx, m));
    float sm = 0.f;
    float ev[9];
    int t = 0;
    for (int c = j; c < SS; c += 16, t++) { float e = expf(Sst[g][c] - mx); ev[t] = e; sm += e; }
    #pragma unroll
    for (int m = 1; m < 16; m <<= 1) sm += __shfl_xor(sm, m);
    float inv = 1.f / sm;
    u16* pr = probs + ((size_t)b * SS + i0 + g) * SP;
    t = 0;
    for (int c = j; c < SP; c += 16, t++) {
        float val = (c < SS) ? ev[t < 9 ? t : 8] * inv : 0.f;
        pr[c] = f2bf(val);
    }
}

// ---- 5. out = probs @ v -> fp32 out (vT pad cols hit zero probs) --------
__global__ __launch_bounds__(256) void pv_k(
    const u16* __restrict__ probs, const u16* __restrict__ vT, float* __restrict__ out) {
    int cb = blockIdx.x, it = blockIdx.y, b = blockIdx.z;
    int tid = threadIdx.x, lane = tid & 63, wv = tid >> 6;
    int lr = lane & 15, lq = lane >> 4;
    const u16* pr = probs + ((size_t)b * SS + it * 16) * SP;
    const u16* vt = vT + (size_t)b * DD * SP;
    int col0 = cb * 256 + wv * 64;

    floatx4 zero4 = {0.f, 0.f, 0.f, 0.f};
    floatx4 acc[4] = {zero4, zero4, zero4, zero4};
    for (int k0 = 0; k0 < SP; k0 += 32) {
        short8 a = *(const short8*)&pr[(size_t)lr * SP + k0 + lq * 8];
        #pragma unroll
        for (int c = 0; c < 4; c++) {
            short8 bb = *(const short8*)&vt[(size_t)(col0 + c * 16 + lr) * SP + k0 + lq * 8];
            acc[c] = MFMA(a, bb, acc[c]);
        }
    }
    #pragma unroll
    for (int c = 0; c < 4; c++)
        #pragma unroll
        for (int i = 0; i < 4; i++) {
            int row = it * 16 + lq * 4 + i, col = col0 + c * 16 + lr;
            out[((size_t)b * SS + row) * DD + col] = acc[c][i];
        }
}

extern "C" void kernel_launch(void* const* d_in, const int* in_sizes, int n_in,
                              void* d_out, int out_size, void* d_ws, size_t ws_size,
                              hipStream_t stream) {
    const float* query = (const float*)d_in[0];
    const float* key_  = (const float*)d_in[1];
    const float* value = (const float*)d_in[2];
    const float* Wq = (const float*)d_in[3];
    const float* bq = (const float*)d_in[4];
    const float* Wk = (const float*)d_in[5];
    const float* bk = (const float*)d_in[6];
    const float* Wv = (const float*)d_in[7];
    const float* bv = (const float*)d_in[8];
    const float* Wl = (const float*)d_in[9];
    const float* bl = (const float*)d_in[10];
    const float* wg = (const float*)d_in[11];

    // ws layout (bf16 elements unless noted)
    u16* WT    = (u16*)d_ws;                              // 3*1024*1024
    u16* Xv    = WT + (size_t)3 * DD * DD;                // 18432*1024 (value bf16)
    u16* q     = Xv + (size_t)NB * SS * DD;               // 18432*1024
    u16* k     = q  + (size_t)NB * SS * DD;
    u16* vT    = k  + (size_t)NB * SS * DD;               // 128*1024*160
    u16* probs = vT + (size_t)NB * DD * SP;               // 128*144*160
    float* biasb = (float*)(probs + (size_t)NB * SS * SP);// 144*144 f32

    // d_out (75.5 MB fp32) is dead until pv_k -> bf16 scratch for
    // converted query/key (exactly 2 * 128*144*1024 * 2B).
    u16* Xq = (u16*)d_out;
    u16* Xk = Xq + (size_t)NB * SS * DD;

    transpose_w_k<<<dim3(32, 32, 3), 256, 0, stream>>>(Wq, Wk, Wv, WT);
    bias_k<<<dim3(SS * SS), 64, 0, stream>>>(Wl, bl, wg, biasb);

    int nchunk = NB * SS * DD / 8;
    convert3_k<<<dim3(1024, 3), 256, 0, stream>>>(query, key_, value, Xq, Xk, Xv, nchunk);
    proj_k<<<dim3(8, 144, 3), 256, 0, stream>>>(Xq, Xk, Xv, WT, bq, bk, bv, q, k, vT);

    attn_k<<<dim3(9, NB), 256, 0, stream>>>(q, k, biasb, probs);
    pv_k<<<dim3(4, 9, NB), 256, 0, stream>>>(probs, vT, (float*)d_out);
}